// Round 1
// baseline (559.256 us; speedup 1.0000x reference)
//
#include <hip/hip_runtime.h>

#define ROWS 1048576
#define BINS 17
#define ROWS_PER_BLOCK 256
#define GROUPS_PER_BLOCK 64   // ROWS_PER_BLOCK / 4
#define CONV_N 33             // 2*BINS - 1

// One thread = one row. Block stages 256 rows of pred+soft into LDS (coalesced
// float4), computes per-row KL + target softmax, then 64 conv groups (4 rows
// each, wholly block-local) produce the 33-wide ratio rows.
__global__ __launch_bounds__(256) void kd_main(
    const float* __restrict__ pred,
    const float* __restrict__ soft,
    const float* __restrict__ weight,
    float* __restrict__ out,
    float* __restrict__ acc)
{
    __shared__ float sA[ROWS_PER_BLOCK * BINS];  // pred tile, later target softmax
    __shared__ float sB[ROWS_PER_BLOCK * BINS];  // soft tile
    const int tid = threadIdx.x;
    const long long base = (long long)blockIdx.x * (ROWS_PER_BLOCK * BINS);

    // ---- coalesced staging: 17408 B per tile, base 16B-aligned ----
    const float4* p4 = reinterpret_cast<const float4*>(pred + base);
    const float4* q4 = reinterpret_cast<const float4*>(soft + base);
    float4* a4 = reinterpret_cast<float4*>(sA);
    float4* b4 = reinterpret_cast<float4*>(sB);
#pragma unroll
    for (int k = 0; k < 4; ++k) {
        a4[k * 256 + tid] = p4[k * 256 + tid];
        b4[k * 256 + tid] = q4[k * 256 + tid];
    }
    if (tid < 64) {  // remaining 64 float4 of the 1088
        a4[1024 + tid] = p4[1024 + tid];
        b4[1024 + tid] = q4[1024 + tid];
    }
    __syncthreads();

    // ---- per-row math (row = tid). Row stride 17 floats (odd): 2-way bank
    // aliasing only, free on gfx950. ----
    float x[BINS], y[BINS];
#pragma unroll
    for (int j = 0; j < BINS; ++j) {
        x[j] = sA[tid * BINS + j];
        y[j] = sB[tid * BINS + j];
    }

    float sx = 0.f, sy = 0.f;
#pragma unroll
    for (int j = 0; j < BINS; ++j) { sx += x[j]; sy += y[j]; }
    const float mx = sx * (1.0f / BINS);
    const float my = sy * (1.0f / BINS);

    float vx = 0.f, vy = 0.f;
#pragma unroll
    for (int j = 0; j < BINS; ++j) {
        const float dx = x[j] - mx; vx += dx * dx;
        const float dy = y[j] - my; vy += dy * dy;
    }
    // (x - mean) / (eps + std_ddof1)  then  / T  -> fold T into the scale
    const float invsx = 0.1f / (1e-7f + sqrtf(vx * (1.0f / (BINS - 1))));
    const float invsy = 0.1f / (1e-7f + sqrtf(vy * (1.0f / (BINS - 1))));

    float a[BINS], b[BINS];
    float amax = -1e30f, bmax = -1e30f;
#pragma unroll
    for (int j = 0; j < BINS; ++j) {
        a[j] = (x[j] - mx) * invsx;
        b[j] = (y[j] - my) * invsy;
        amax = fmaxf(amax, a[j]);
        bmax = fmaxf(bmax, b[j]);
    }
    float sea = 0.f, seb = 0.f;
    float eb[BINS];
#pragma unroll
    for (int j = 0; j < BINS; ++j) {
        sea += __expf(a[j] - amax);
        eb[j] = __expf(b[j] - bmax);
        seb += eb[j];
    }
    const float la = __logf(sea);
    const float lb = __logf(seb);
    const float invseb = 1.0f / seb;

    float kl = 0.f;
#pragma unroll
    for (int j = 0; j < BINS; ++j) {
        const float log_ps = a[j] - amax - la;
        const float log_pt = b[j] - bmax - lb;
        kl += (eb[j] * invseb) * (log_pt - log_ps);
    }

    // ---- target = softmax(raw soft_label) -> overwrite OWN row of sA.
    // Safe without a barrier: each thread reads/writes only row `tid`. ----
    float ymax = -1e30f;
#pragma unroll
    for (int j = 0; j < BINS; ++j) ymax = fmaxf(ymax, y[j]);
    float ts = 0.f;
    float ty[BINS];
#pragma unroll
    for (int j = 0; j < BINS; ++j) { ty[j] = __expf(y[j] - ymax); ts += ty[j]; }
    const float invts = 1.0f / ts;
#pragma unroll
    for (int j = 0; j < BINS; ++j) sA[tid * BINS + j] = ty[j] * invts;

    // ---- wave-level reduce of KL and weight, one atomic pair per wave ----
    float w = weight[blockIdx.x * ROWS_PER_BLOCK + tid];
    float k2 = kl, w2 = w;
#pragma unroll
    for (int off = 32; off >= 1; off >>= 1) {
        k2 += __shfl_down(k2, off, 64);
        w2 += __shfl_down(w2, off, 64);
    }
    if ((tid & 63) == 0) {
        atomicAdd(&acc[0], k2);
        atomicAdd(&acc[1], w2);
    }

    __syncthreads();  // target rows visible to conv stage

    // ---- full convolutions per 4-row group; 64*33 = 2112 outputs/block ----
    for (int idx = tid; idx < GROUPS_PER_BLOCK * CONV_N; idx += 256) {
        const int g = idx / CONV_N;
        const int j = idx - g * CONV_N;
        const float* t0 = &sA[(4 * g + 0) * BINS];  // top
        const float* t1 = t0 + BINS;                // bottom
        const float* t2 = t1 + BINS;                // left
        const float* t3 = t2 + BINS;                // right
        const int kmin = (j - (BINS - 1) > 0) ? (j - (BINS - 1)) : 0;
        const int kmax = (j < BINS - 1) ? j : (BINS - 1);
        float slr = 0.f, stb = 0.f;
        for (int k = kmin; k <= kmax; ++k) {
            slr += t2[k] * t3[j - k];
            stb += t0[k] * t1[j - k];
        }
        out[1 + ((long long)blockIdx.x * GROUPS_PER_BLOCK + g) * CONV_N + j] =
            slr / (stb + 1e-8f);
    }
}

__global__ void kd_finalize(const float* __restrict__ acc, float* __restrict__ out)
{
    // loss = LOSS_WEIGHT * T^2 * mean_rows(KL) * mean(weight)
    out[0] = 100.0f * (acc[0] * (1.0f / ROWS)) * (acc[1] * (1.0f / ROWS));
}

extern "C" void kernel_launch(void* const* d_in, const int* in_sizes, int n_in,
                              void* d_out, int out_size, void* d_ws, size_t ws_size,
                              hipStream_t stream)
{
    const float* pred   = (const float*)d_in[0];
    const float* soft   = (const float*)d_in[1];
    const float* weight = (const float*)d_in[2];
    float* out = (float*)d_out;
    float* acc = (float*)d_ws;

    hipMemsetAsync(acc, 0, 2 * sizeof(float), stream);
    kd_main<<<ROWS / ROWS_PER_BLOCK, ROWS_PER_BLOCK, 0, stream>>>(pred, soft, weight, out, acc);
    kd_finalize<<<1, 1, 0, stream>>>(acc, out);
}

// Round 2
// 256.208 us; speedup vs baseline: 2.1828x; 2.1828x over previous
//
#include <hip/hip_runtime.h>

#define ROWS 1048576
#define BINS 17
#define ROWS_PER_BLOCK 256
#define GROUPS_PER_BLOCK 64   // ROWS_PER_BLOCK / 4
#define CONV_N 33             // 2*BINS - 1

// One thread = one row. Only TWO private arrays (x,y = 34 floats) so the
// compiler promotes them to VGPRs (round-1 version had 102 floats -> scratch
// spill -> 439us latency-bound). Everything else recomputed algebraically:
//   max of normalized logits = (max(raw) - mean) * invscale  (scale > 0)
//   exp() recomputed per pass instead of stored.
__global__ __launch_bounds__(256) void kd_main(
    const float* __restrict__ pred,
    const float* __restrict__ soft,
    const float* __restrict__ weight,
    float* __restrict__ out,
    float* __restrict__ acc)
{
    __shared__ float sA[ROWS_PER_BLOCK * BINS];  // pred tile, later target softmax
    __shared__ float sB[ROWS_PER_BLOCK * BINS];  // soft tile
    __shared__ float red[8];                     // 4 waves x {kl, w}
    const int tid = threadIdx.x;
    const long long base = (long long)blockIdx.x * (ROWS_PER_BLOCK * BINS);

    // ---- coalesced staging: 17408 B per tile, base 16B-aligned ----
    const float4* p4 = reinterpret_cast<const float4*>(pred + base);
    const float4* q4 = reinterpret_cast<const float4*>(soft + base);
    float4* a4 = reinterpret_cast<float4*>(sA);
    float4* b4 = reinterpret_cast<float4*>(sB);
#pragma unroll
    for (int k = 0; k < 4; ++k) {
        a4[k * 256 + tid] = p4[k * 256 + tid];
        b4[k * 256 + tid] = q4[k * 256 + tid];
    }
    if (tid < 64) {  // remaining 64 float4 of the 1088
        a4[1024 + tid] = p4[1024 + tid];
        b4[1024 + tid] = q4[1024 + tid];
    }
    const float w = weight[blockIdx.x * ROWS_PER_BLOCK + tid];
    __syncthreads();

    // ---- per-row math (row = tid); stride 17 (odd) -> 2-way bank alias, free
    float x[BINS], y[BINS];
    float sx = 0.f, sy = 0.f, xmx = -1e30f, ymx = -1e30f;
#pragma unroll
    for (int j = 0; j < BINS; ++j) {
        x[j] = sA[tid * BINS + j];
        y[j] = sB[tid * BINS + j];
        sx += x[j]; sy += y[j];
        xmx = fmaxf(xmx, x[j]); ymx = fmaxf(ymx, y[j]);
    }
    const float mx = sx * (1.0f / BINS);
    const float my = sy * (1.0f / BINS);

    float vx = 0.f, vy = 0.f;
#pragma unroll
    for (int j = 0; j < BINS; ++j) {
        const float dx = x[j] - mx; vx = fmaf(dx, dx, vx);
        const float dy = y[j] - my; vy = fmaf(dy, dy, vy);
    }
    // (x - mean)/(eps + std_ddof1) / T  -> fold 1/T into scale (scale > 0)
    const float invsx = 0.1f / (1e-7f + sqrtf(vx * (1.0f / (BINS - 1))));
    const float invsy = 0.1f / (1e-7f + sqrtf(vy * (1.0f / (BINS - 1))));
    const float amax = (xmx - mx) * invsx;   // max of student-normalized logits
    const float bmax = (ymx - my) * invsy;   // max of teacher-normalized logits

    float sea = 0.f, seb = 0.f, ts = 0.f;
#pragma unroll
    for (int j = 0; j < BINS; ++j) {
        sea += __expf((x[j] - mx) * invsx - amax);
        seb += __expf((y[j] - my) * invsy - bmax);
        ts  += __expf(y[j] - ymx);           // target softmax (raw y)
    }
    const float la = __logf(sea);
    const float lb = __logf(seb);
    const float invseb = 1.0f / seb;
    const float invts  = 1.0f / ts;

    float kl = 0.f;
#pragma unroll
    for (int j = 0; j < BINS; ++j) {
        const float aj = (x[j] - mx) * invsx - amax;  // log-sum pending
        const float bj = (y[j] - my) * invsy - bmax;
        kl = fmaf(__expf(bj), (bj - lb) - (aj - la), kl);
    }
    kl *= invseb;

    // target softmax -> overwrite OWN row of sA (no barrier needed: own row)
#pragma unroll
    for (int j = 0; j < BINS; ++j)
        sA[tid * BINS + j] = __expf(y[j] - ymx) * invts;

    // ---- wave shuffle-reduce, then block reduce, 2 atomics per BLOCK ----
    float k2 = kl, w2 = w;
#pragma unroll
    for (int off = 32; off >= 1; off >>= 1) {
        k2 += __shfl_down(k2, off, 64);
        w2 += __shfl_down(w2, off, 64);
    }
    if ((tid & 63) == 0) {
        red[(tid >> 6) * 2 + 0] = k2;
        red[(tid >> 6) * 2 + 1] = w2;
    }

    __syncthreads();  // publishes softmax rows AND red[]

    if (tid == 0) {
        atomicAdd(&acc[0], red[0] + red[2] + red[4] + red[6]);
        atomicAdd(&acc[1], red[1] + red[3] + red[5] + red[7]);
    }

    // ---- full convolutions per 4-row group; 64*33 = 2112 outputs/block ----
    for (int idx = tid; idx < GROUPS_PER_BLOCK * CONV_N; idx += 256) {
        const int g = idx / CONV_N;
        const int j = idx - g * CONV_N;
        const float* t0 = &sA[(4 * g + 0) * BINS];  // top
        const float* t1 = t0 + BINS;                // bottom
        const float* t2 = t1 + BINS;                // left
        const float* t3 = t2 + BINS;                // right
        const int kmin = (j - (BINS - 1) > 0) ? (j - (BINS - 1)) : 0;
        const int kmax = (j < BINS - 1) ? j : (BINS - 1);
        float slr = 0.f, stb = 0.f;
        for (int k = kmin; k <= kmax; ++k) {
            slr = fmaf(t2[k], t3[j - k], slr);
            stb = fmaf(t0[k], t1[j - k], stb);
        }
        out[1 + ((long long)blockIdx.x * GROUPS_PER_BLOCK + g) * CONV_N + j] =
            slr / (stb + 1e-8f);
    }
}

__global__ void kd_finalize(const float* __restrict__ acc, float* __restrict__ out)
{
    // loss = LOSS_WEIGHT * T^2 * mean_rows(KL) * mean(weight)
    out[0] = 100.0f * (acc[0] * (1.0f / ROWS)) * (acc[1] * (1.0f / ROWS));
}

extern "C" void kernel_launch(void* const* d_in, const int* in_sizes, int n_in,
                              void* d_out, int out_size, void* d_ws, size_t ws_size,
                              hipStream_t stream)
{
    const float* pred   = (const float*)d_in[0];
    const float* soft   = (const float*)d_in[1];
    const float* weight = (const float*)d_in[2];
    float* out = (float*)d_out;
    float* acc = (float*)d_ws;

    hipMemsetAsync(acc, 0, 2 * sizeof(float), stream);
    kd_main<<<ROWS / ROWS_PER_BLOCK, ROWS_PER_BLOCK, 0, stream>>>(pred, soft, weight, out, acc);
    kd_finalize<<<1, 1, 0, stream>>>(acc, out);
}

// Round 3
// 245.886 us; speedup vs baseline: 2.2745x; 1.0420x over previous
//
#include <hip/hip_runtime.h>

#define ROWS 1048576
#define BINS 17
#define ROWS_PER_BLOCK 256
#define GROUPS_PER_BLOCK 64   // ROWS_PER_BLOCK / 4
#define CONV_N 33             // 2*BINS - 1

// Phase 1: one thread = one row (256 rows/block). Stage pred+soft to LDS with
// float4, per-row normalize + KL + target softmax (softmax written back to sA).
// Phase 2: one thread = one (group, conv-side). 128 threads each load two
// adjacent softmax rows (17 x float2, 8B-aligned, contiguous) and compute the
// full 33-tap convolution as a fully-unrolled 17x17 FMA outer product in
// registers (static indices only -> no scratch, no divergent trip counts, no
// per-lane irregular LDS addressing -- round-2's 8M bank-conflict cycles came
// from the old runtime-bound inner loop). slr/stb live in adjacent lanes;
// exchange via 33 static shfls, divide, restage to LDS (overlaying dead sB),
// coalesced store.
__global__ __launch_bounds__(256) void kd_main(
    const float* __restrict__ pred,
    const float* __restrict__ soft,
    const float* __restrict__ weight,
    float* __restrict__ out,
    float* __restrict__ acc)
{
    __shared__ float sA[ROWS_PER_BLOCK * BINS];  // pred tile -> target softmax
    __shared__ float sB[ROWS_PER_BLOCK * BINS];  // soft tile -> ratio restage
    __shared__ float red[8];                     // 4 waves x {kl, w}
    const int tid = threadIdx.x;
    const long long base = (long long)blockIdx.x * (ROWS_PER_BLOCK * BINS);

    // ---- coalesced staging: 17408 B per tile, base 16B-aligned ----
    const float4* p4 = reinterpret_cast<const float4*>(pred + base);
    const float4* q4 = reinterpret_cast<const float4*>(soft + base);
    float4* a4 = reinterpret_cast<float4*>(sA);
    float4* b4 = reinterpret_cast<float4*>(sB);
#pragma unroll
    for (int k = 0; k < 4; ++k) {
        a4[k * 256 + tid] = p4[k * 256 + tid];
        b4[k * 256 + tid] = q4[k * 256 + tid];
    }
    if (tid < 64) {  // remaining 64 float4 of the 1088
        a4[1024 + tid] = p4[1024 + tid];
        b4[1024 + tid] = q4[1024 + tid];
    }
    const float w = weight[blockIdx.x * ROWS_PER_BLOCK + tid];
    __syncthreads();

    // ---- per-row math (row = tid); stride 17 (odd) -> 2-way bank alias, free
    float x[BINS], y[BINS];
    float sx = 0.f, sy = 0.f, xmx = -1e30f, ymx = -1e30f;
#pragma unroll
    for (int j = 0; j < BINS; ++j) {
        x[j] = sA[tid * BINS + j];
        y[j] = sB[tid * BINS + j];
        sx += x[j]; sy += y[j];
        xmx = fmaxf(xmx, x[j]); ymx = fmaxf(ymx, y[j]);
    }
    const float mx = sx * (1.0f / BINS);
    const float my = sy * (1.0f / BINS);

    float vx = 0.f, vy = 0.f;
#pragma unroll
    for (int j = 0; j < BINS; ++j) {
        const float dx = x[j] - mx; vx = fmaf(dx, dx, vx);
        const float dy = y[j] - my; vy = fmaf(dy, dy, vy);
    }
    // (x - mean)/(eps + std_ddof1) / T  -> fold 1/T into scale (scale > 0)
    const float invsx = 0.1f / (1e-7f + sqrtf(vx * (1.0f / (BINS - 1))));
    const float invsy = 0.1f / (1e-7f + sqrtf(vy * (1.0f / (BINS - 1))));
    const float amax = (xmx - mx) * invsx;
    const float bmax = (ymx - my) * invsy;

    float sea = 0.f, seb = 0.f, ts = 0.f;
#pragma unroll
    for (int j = 0; j < BINS; ++j) {
        sea += __expf((x[j] - mx) * invsx - amax);
        seb += __expf((y[j] - my) * invsy - bmax);
        ts  += __expf(y[j] - ymx);           // target softmax (raw y)
    }
    const float la = __logf(sea);
    const float lb = __logf(seb);
    const float invseb = 1.0f / seb;
    const float invts  = 1.0f / ts;

    float kl = 0.f;
#pragma unroll
    for (int j = 0; j < BINS; ++j) {
        const float aj = (x[j] - mx) * invsx - amax;
        const float bj = (y[j] - my) * invsy - bmax;
        kl = fmaf(__expf(bj), (bj - lb) - (aj - la), kl);
    }
    kl *= invseb;

    // target softmax -> overwrite OWN row of sA (no barrier needed: own row)
#pragma unroll
    for (int j = 0; j < BINS; ++j)
        sA[tid * BINS + j] = __expf(y[j] - ymx) * invts;

    // ---- wave shuffle-reduce, then block reduce, 2 atomics per BLOCK ----
    float k2 = kl, w2 = w;
#pragma unroll
    for (int off = 32; off >= 1; off >>= 1) {
        k2 += __shfl_down(k2, off, 64);
        w2 += __shfl_down(w2, off, 64);
    }
    if ((tid & 63) == 0) {
        red[(tid >> 6) * 2 + 0] = k2;
        red[(tid >> 6) * 2 + 1] = w2;
    }

    __syncthreads();  // publishes softmax rows, red[], and retires sB reads

    if (tid == 0) {
        atomicAdd(&acc[0], red[0] + red[2] + red[4] + red[6]);
        atomicAdd(&acc[1], red[1] + red[3] + red[5] + red[7]);
    }

    float* sR = sB;  // soft tile is dead; reuse as ratio staging (need 2112)

    // ---- conv: threads 0..127 (waves 0-1). t even: left*right rows (4g+2,3)
    //      t odd: top*bottom rows (4g+0,1). Rows 2u,2u+1 are 34 contiguous
    //      floats at 8B-aligned LDS offset -> 17 float2 reads. ----
    if (tid < 2 * GROUPS_PER_BLOCK) {
        const int g = tid >> 1;
        const int R = 4 * g + ((tid & 1) ? 0 : 2);   // even lane: lr rows
        float f[2 * BINS];
        const float2* pr = reinterpret_cast<const float2*>(&sA[R * BINS]);
#pragma unroll
        for (int i = 0; i < BINS; ++i) {
            const float2 v = pr[i];
            f[2 * i] = v.x; f[2 * i + 1] = v.y;
        }
        float accv[CONV_N];
#pragma unroll
        for (int j = 0; j < CONV_N; ++j) accv[j] = 0.f;
#pragma unroll
        for (int k = 0; k < BINS; ++k)
#pragma unroll
            for (int m = 0; m < BINS; ++m)
                accv[k + m] = fmaf(f[k], f[BINS + m], accv[k + m]);

        // adjacent-lane exchange: even lane holds slr, odd lane holds stb
#pragma unroll
        for (int j = 0; j < CONV_N; ++j) {
            const float o = __shfl_down(accv[j], 1, 64);
            if ((tid & 1) == 0)
                sR[g * CONV_N + j] = accv[j] / (o + 1e-8f);  // stride 33: 2-way
        }
    }
    __syncthreads();

    // ---- coalesced store of the 2112 ratio floats ----
    const long long ob = 1 + (long long)blockIdx.x * (GROUPS_PER_BLOCK * CONV_N);
#pragma unroll
    for (int i = 0; i < 8; ++i)
        out[ob + i * 256 + tid] = sR[i * 256 + tid];
    if (tid < 64) out[ob + 2048 + tid] = sR[2048 + tid];
}

__global__ void kd_finalize(const float* __restrict__ acc, float* __restrict__ out)
{
    // loss = LOSS_WEIGHT * T^2 * mean_rows(KL) * mean(weight)
    out[0] = 100.0f * (acc[0] * (1.0f / ROWS)) * (acc[1] * (1.0f / ROWS));
}

extern "C" void kernel_launch(void* const* d_in, const int* in_sizes, int n_in,
                              void* d_out, int out_size, void* d_ws, size_t ws_size,
                              hipStream_t stream)
{
    const float* pred   = (const float*)d_in[0];
    const float* soft   = (const float*)d_in[1];
    const float* weight = (const float*)d_in[2];
    float* out = (float*)d_out;
    float* acc = (float*)d_ws;

    hipMemsetAsync(acc, 0, 2 * sizeof(float), stream);
    kd_main<<<ROWS / ROWS_PER_BLOCK, ROWS_PER_BLOCK, 0, stream>>>(pred, soft, weight, out, acc);
    kd_finalize<<<1, 1, 0, stream>>>(acc, out);
}

// Round 4
// 183.465 us; speedup vs baseline: 3.0483x; 1.3402x over previous
//
#include <hip/hip_runtime.h>

#define ROWS 1048576
#define BINS 17
#define RPB 64                  // rows per block = threads per block (1 wave)
#define NBLK (ROWS / RPB)       // 16384 blocks
#define GPB (RPB / 4)           // 16 conv groups per block
#define CONV_N 33               // 2*BINS - 1

// One wave per block, 64 rows. 8.7 KB LDS/block -> ~18 blocks/CU co-resident
// (round-3 used 34.8 KB -> 2.7 blocks and was latency-bound at 850 GB/s with
// 80% stall). Single-wave blocks: barriers are near-free, every block is an
// independent staging stream -> ~6x more bytes in flight.
// PART=true: per-block (kl,w) partials into ws (no atomics, no memset).
template <bool PART>
__global__ __launch_bounds__(64, 4) void kd_main(
    const float* __restrict__ pred,
    const float* __restrict__ soft,
    const float* __restrict__ weight,
    float* __restrict__ out,
    float* __restrict__ ws)
{
    __shared__ float sA[RPB * BINS];  // pred tile -> target softmax
    __shared__ float sB[RPB * BINS];  // soft tile -> ratio restage
    const int tid = threadIdx.x;
    const long long base = (long long)blockIdx.x * (RPB * BINS);

    // ---- coalesced staging: 272 float4 per tile, base 4352B-aligned ----
    const float4* p4 = reinterpret_cast<const float4*>(pred + base);
    const float4* q4 = reinterpret_cast<const float4*>(soft + base);
    float4* a4 = reinterpret_cast<float4*>(sA);
    float4* b4 = reinterpret_cast<float4*>(sB);
#pragma unroll
    for (int k = 0; k < 4; ++k) {
        a4[k * 64 + tid] = p4[k * 64 + tid];
        b4[k * 64 + tid] = q4[k * 64 + tid];
    }
    if (tid < 16) {
        a4[256 + tid] = p4[256 + tid];
        b4[256 + tid] = q4[256 + tid];
    }
    const float w = weight[blockIdx.x * RPB + tid];
    __syncthreads();

    // ---- per-row math (row = tid); stride 17 (odd) -> 2-way alias, free ----
    float x[BINS], y[BINS];
    float sx = 0.f, sy = 0.f, xmx = -1e30f, ymx = -1e30f;
#pragma unroll
    for (int j = 0; j < BINS; ++j) {
        x[j] = sA[tid * BINS + j];
        y[j] = sB[tid * BINS + j];
        sx += x[j]; sy += y[j];
        xmx = fmaxf(xmx, x[j]); ymx = fmaxf(ymx, y[j]);
    }
    const float mx = sx * (1.0f / BINS);
    const float my = sy * (1.0f / BINS);

    float vx = 0.f, vy = 0.f;
#pragma unroll
    for (int j = 0; j < BINS; ++j) {
        const float dx = x[j] - mx; vx = fmaf(dx, dx, vx);
        const float dy = y[j] - my; vy = fmaf(dy, dy, vy);
    }
    // (x - mean)/(eps + std_ddof1) / T : fold 1/T into positive scale
    const float invsx = 0.1f / (1e-7f + sqrtf(vx * (1.0f / (BINS - 1))));
    const float invsy = 0.1f / (1e-7f + sqrtf(vy * (1.0f / (BINS - 1))));
    const float amax = (xmx - mx) * invsx;
    const float bmax = (ymx - my) * invsy;

    float sea = 0.f, seb = 0.f, ts = 0.f;
#pragma unroll
    for (int j = 0; j < BINS; ++j) {
        sea += __expf((x[j] - mx) * invsx - amax);
        seb += __expf((y[j] - my) * invsy - bmax);
        ts  += __expf(y[j] - ymx);           // target softmax on raw y
    }
    const float la = __logf(sea);
    const float lb = __logf(seb);
    const float invseb = 1.0f / seb;
    const float invts  = 1.0f / ts;

    float kl = 0.f;
#pragma unroll
    for (int j = 0; j < BINS; ++j) {
        const float aj = (x[j] - mx) * invsx - amax;
        const float bj = (y[j] - my) * invsy - bmax;
        kl = fmaf(__expf(bj), (bj - lb) - (aj - la), kl);
    }
    kl *= invseb;

    // target softmax -> overwrite OWN row of sA (own-row, no barrier needed)
#pragma unroll
    for (int j = 0; j < BINS; ++j)
        sA[tid * BINS + j] = __expf(y[j] - ymx) * invts;

    // ---- wave reduce kl & weight; one non-atomic partial pair per block ----
    float k2 = kl, w2 = w;
#pragma unroll
    for (int off = 32; off >= 1; off >>= 1) {
        k2 += __shfl_down(k2, off, 64);
        w2 += __shfl_down(w2, off, 64);
    }

    __syncthreads();  // publish softmax rows (single wave: cheap)

    float* sR = sB;  // soft tile dead; reuse as ratio staging (528 floats)

    // ---- conv: tid<32. even lane: left*right rows (4g+2,3); odd: top*bottom
    //      rows (4g+0,1). Row pair = 34 contiguous floats, 8B-aligned. ----
    if (tid < 2 * GPB) {
        const int g = tid >> 1;
        const int R = 4 * g + ((tid & 1) ? 0 : 2);
        float f[2 * BINS];
        const float2* pr = reinterpret_cast<const float2*>(&sA[R * BINS]);
#pragma unroll
        for (int i = 0; i < BINS; ++i) {
            const float2 v = pr[i];
            f[2 * i] = v.x; f[2 * i + 1] = v.y;
        }
        float accv[CONV_N];
#pragma unroll
        for (int j = 0; j < CONV_N; ++j) accv[j] = 0.f;
#pragma unroll
        for (int k = 0; k < BINS; ++k)
#pragma unroll
            for (int m = 0; m < BINS; ++m)
                accv[k + m] = fmaf(f[k], f[BINS + m], accv[k + m]);

        // adjacent-lane exchange: even lane = slr, odd lane = stb
#pragma unroll
        for (int j = 0; j < CONV_N; ++j) {
            const float o = __shfl_down(accv[j], 1, 64);
            if ((tid & 1) == 0)
                sR[g * CONV_N + j] = accv[j] / (o + 1e-8f);
        }
    }
    __syncthreads();

    // ---- coalesced store of the 528 ratio floats ----
    const long long ob = 1 + (long long)blockIdx.x * (GPB * CONV_N);
#pragma unroll
    for (int i = 0; i < 8; ++i)
        out[ob + i * 64 + tid] = sR[i * 64 + tid];
    if (tid < 16) out[ob + 512 + tid] = sR[512 + tid];

    // ---- scalar-path partials, AFTER all barriers (no barrier waits) ----
    if (tid == 0) {
        if (PART) {
            ws[blockIdx.x]        = k2;
            ws[NBLK + blockIdx.x] = w2;
        } else {
            atomicAdd(&ws[0], k2);
            atomicAdd(&ws[1], w2);
        }
    }
}

// PART=true: reduce 2*16384 partials; else just combine the two atomics.
template <bool PART>
__global__ __launch_bounds__(1024) void kd_reduce(
    const float* __restrict__ ws, float* __restrict__ out)
{
    if (!PART) {
        if (threadIdx.x == 0)
            out[0] = 100.0f * (ws[0] * (1.0f / ROWS)) * (ws[1] * (1.0f / ROWS));
        return;
    }
    __shared__ float red[32];
    const int tid = threadIdx.x;
    const float4* k4 = reinterpret_cast<const float4*>(ws);          // 4096 f4
    const float4* w4 = reinterpret_cast<const float4*>(ws + NBLK);   // 4096 f4
    float ks = 0.f, wsum = 0.f;
#pragma unroll
    for (int i = 0; i < 4; ++i) {
        const float4 a = k4[i * 1024 + tid];
        const float4 b = w4[i * 1024 + tid];
        ks += (a.x + a.y) + (a.z + a.w);
        wsum += (b.x + b.y) + (b.z + b.w);
    }
#pragma unroll
    for (int off = 32; off >= 1; off >>= 1) {
        ks += __shfl_down(ks, off, 64);
        wsum += __shfl_down(wsum, off, 64);
    }
    if ((tid & 63) == 0) {
        red[(tid >> 6) * 2 + 0] = ks;
        red[(tid >> 6) * 2 + 1] = wsum;
    }
    __syncthreads();
    if (tid == 0) {
        float K = 0.f, W = 0.f;
#pragma unroll
        for (int i = 0; i < 16; ++i) { K += red[2 * i]; W += red[2 * i + 1]; }
        out[0] = 100.0f * (K * (1.0f / ROWS)) * (W * (1.0f / ROWS));
    }
}

extern "C" void kernel_launch(void* const* d_in, const int* in_sizes, int n_in,
                              void* d_out, int out_size, void* d_ws, size_t ws_size,
                              hipStream_t stream)
{
    const float* pred   = (const float*)d_in[0];
    const float* soft   = (const float*)d_in[1];
    const float* weight = (const float*)d_in[2];
    float* out = (float*)d_out;
    float* ws  = (float*)d_ws;

    if (ws_size >= (size_t)(2 * NBLK) * sizeof(float)) {
        kd_main<true><<<NBLK, RPB, 0, stream>>>(pred, soft, weight, out, ws);
        kd_reduce<true><<<1, 1024, 0, stream>>>(ws, out);
    } else {
        hipMemsetAsync(ws, 0, 2 * sizeof(float), stream);
        kd_main<false><<<NBLK, RPB, 0, stream>>>(pred, soft, weight, out, ws);
        kd_reduce<false><<<1, 1024, 0, stream>>>(ws, out);
    }
}